// Round 4
// baseline (482.470 us; speedup 1.0000x reference)
//
#include <hip/hip_runtime.h>
#include <hip/hip_fp16.h>

#define NLAB 30000
#define HID  1024
#define NB   256
#define NE   (NLAB - 1)

#define ROWB   NB      // blocks that own a batch row (row phase)
#define BLOCKS 512     // total blocks = 2 per CU, one scheduling round
#define CHUNK  2       // edges per work-steal grab

// float block reduce, BLK threads (BLK/64 waves)
template <int BLK>
__device__ __forceinline__ float blockReduceSum(float v) {
#pragma unroll
    for (int off = 32; off > 0; off >>= 1)
        v += __shfl_down(v, off, 64);
    __shared__ float smem[BLK / 64];
    const int lane = threadIdx.x & 63;
    const int wid  = threadIdx.x >> 6;
    __syncthreads();
    if (lane == 0) smem[wid] = v;
    __syncthreads();
    float r = 0.f;
    if (threadIdx.x == 0) {
#pragma unroll
        for (int i = 0; i < BLK / 64; ++i) r += smem[i];
    }
    return r;
}

__device__ __forceinline__ double blockReduceSumD256(double v) {
#pragma unroll
    for (int off = 32; off > 0; off >>= 1)
        v += __shfl_down(v, off, 64);
    __shared__ double smem[4];
    const int lane = threadIdx.x & 63;
    const int wid  = threadIdx.x >> 6;
    __syncthreads();
    if (lane == 0) smem[wid] = v;
    __syncthreads();
    double r = 0.0;
    if (threadIdx.x == 0) r = smem[0] + smem[1] + smem[2] + smem[3];
    return r;
}

// ws re-poisoned to 0xAA each launch -> zero the steal counter ourselves.
__global__ void init_kernel(int* ctr) { *ctr = 0; }

// ---------------------------------------------------------------------------
// Fused kernel:
//   blocks [0,256): row phase first — BCE partial + fp16 sigmoid row in LDS
//                   (60 KB) + prob_reg edge lookups from LDS.
//   ALL blocks then: rec phase — per-wave work-stealing over edges; one WAVE
//                   per edge, lane l holds float4 cols {l,l+64,l+128,l+192}
//                   of both rows = 8 independent 16B loads in flight.
// Every block writes its 3 partials to ws slots (overwrites poison; no init).
// ---------------------------------------------------------------------------
__global__ __launch_bounds__(1024, 2)
void fused_kernel(const float4* __restrict__ lg4,
                  const float4* __restrict__ tg4,
                  const float4* __restrict__ p4,
                  const int* __restrict__ pidx,
                  const int* __restrict__ cidx,
                  double* __restrict__ slots,
                  int* __restrict__ ctr) {
    __shared__ __half sprob[NLAB];
    const int tid  = threadIdx.x;
    const int bid  = blockIdx.x;
    const int lane = tid & 63;

    float bces = 0.f, recs = 0.f, ps = 0.f;

    if (bid < ROWB) {
        // ---- row phase: BCE + sigmoid staging + prob_reg from LDS ----
        const float4* lrow = lg4 + (size_t)bid * (NLAB / 4);
        const float4* trow = tg4 + (size_t)bid * (NLAB / 4);
        for (int i = tid; i < NLAB / 4; i += 1024) {
            const float4 l = lrow[i];
            const float4 t = trow[i];
            bces += fmaxf(l.x, 0.f) + log1pf(__expf(-fabsf(l.x))) - l.x * t.x;
            bces += fmaxf(l.y, 0.f) + log1pf(__expf(-fabsf(l.y))) - l.y * t.y;
            bces += fmaxf(l.z, 0.f) + log1pf(__expf(-fabsf(l.z))) - l.z * t.z;
            bces += fmaxf(l.w, 0.f) + log1pf(__expf(-fabsf(l.w))) - l.w * t.w;
            sprob[4 * i + 0] = __float2half(1.f / (1.f + __expf(-l.x)));
            sprob[4 * i + 1] = __float2half(1.f / (1.f + __expf(-l.y)));
            sprob[4 * i + 2] = __float2half(1.f / (1.f + __expf(-l.z)));
            sprob[4 * i + 3] = __float2half(1.f / (1.f + __expf(-l.w)));
        }
        __syncthreads();
        for (int e = tid; e < NE; e += 1024) {
            const float d = __half2float(sprob[cidx[e]]) -
                            __half2float(sprob[pidx[e]]);
            ps += d > 0.f ? d : 0.f;
        }
    }

    // ---- rec phase: per-wave work stealing, one wave per edge ----
    for (;;) {
        int base = 0;
        if (lane == 0) base = atomicAdd(ctr, CHUNK);
        base = __shfl(base, 0, 64);
        if (base >= NE) break;
        const int eend = base + CHUNK < NE ? base + CHUNK : NE;
        for (int e = base; e < eend; ++e) {
            const int p = pidx[e];
            const int c = cidx[e];
            const float4* rp = p4 + (size_t)p * (HID / 4) + lane;
            const float4* rc = p4 + (size_t)c * (HID / 4) + lane;
            const float4 a0 = rp[0], a1 = rp[64], a2 = rp[128], a3 = rp[192];
            const float4 b0 = rc[0], b1 = rc[64], b2 = rc[128], b3 = rc[192];
            float dx, dy, dz, dw;
            dx = a0.x - b0.x; dy = a0.y - b0.y; dz = a0.z - b0.z; dw = a0.w - b0.w;
            recs += dx * dx + dy * dy + dz * dz + dw * dw;
            dx = a1.x - b1.x; dy = a1.y - b1.y; dz = a1.z - b1.z; dw = a1.w - b1.w;
            recs += dx * dx + dy * dy + dz * dz + dw * dw;
            dx = a2.x - b2.x; dy = a2.y - b2.y; dz = a2.z - b2.z; dw = a2.w - b2.w;
            recs += dx * dx + dy * dy + dz * dz + dw * dw;
            dx = a3.x - b3.x; dy = a3.y - b3.y; dz = a3.z - b3.z; dw = a3.w - b3.w;
            recs += dx * dx + dy * dy + dz * dz + dw * dw;
        }
    }

    const float rb = blockReduceSum<1024>(bces);
    const float rr = blockReduceSum<1024>(recs);
    const float rp = blockReduceSum<1024>(ps);
    if (tid == 0) {
        slots[bid]              = (double)rb;
        slots[BLOCKS + bid]     = (double)rr;
        slots[2 * BLOCKS + bid] = (double)rp;
    }
}

// finalize: sum the 3 slot arrays, combine, write scalar
__global__ void fin_kernel(const double* __restrict__ slots,
                           float* __restrict__ out) {
    double sb = 0.0, sr = 0.0, sp = 0.0;
    for (int i = threadIdx.x; i < BLOCKS; i += 256) {
        sb += slots[i];
        sr += slots[BLOCKS + i];
        sp += slots[2 * BLOCKS + i];
    }
    sb = blockReduceSumD256(sb);
    sr = blockReduceSumD256(sr);
    sp = blockReduceSumD256(sp);
    if (threadIdx.x == 0) {
        const double bce = sb * (1.0 / ((double)NB * (double)NLAB));
        out[0] = (float)(bce + 5e-5 * sr + 1e-4 * sp);
    }
}

extern "C" void kernel_launch(void* const* d_in, const int* in_sizes, int n_in,
                              void* d_out, int out_size, void* d_ws, size_t ws_size,
                              hipStream_t stream) {
    const float* logits  = (const float*)d_in[0];
    const float* targets = (const float*)d_in[1];
    const float* params  = (const float*)d_in[2];
    const int*   pidx    = (const int*)d_in[3];
    const int*   cidx    = (const int*)d_in[4];
    double* slots = (double*)d_ws;
    int*    ctr   = (int*)((char*)d_ws + 3 * BLOCKS * sizeof(double));
    float*  out   = (float*)d_out;

    init_kernel<<<1, 1, 0, stream>>>(ctr);
    fused_kernel<<<BLOCKS, 1024, 0, stream>>>(
        (const float4*)logits, (const float4*)targets, (const float4*)params,
        pidx, cidx, slots, ctr);
    fin_kernel<<<1, 256, 0, stream>>>(slots, out);
}

// Round 5
// 242.504 us; speedup vs baseline: 1.9895x; 1.9895x over previous
//
#include <hip/hip_runtime.h>
#include <hip/hip_fp16.h>

#define NLAB 30000
#define HID  1024
#define NB   256
#define NE   (NLAB - 1)

#define BLOCKS 512               // 2 per CU, one scheduling round, all identical
#define WAVES_PER_BLK 16
#define TOT_WAVES (BLOCKS * WAVES_PER_BLK)   // 8192
#define NL4 (NLAB / 4)           // 7500 float4 per row
#define HALF4 (NL4 / 2)          // 3750
#define EHALF 15000              // edge split point between the 2 row-sharers

// float block reduce, 1024 threads (16 waves)
__device__ __forceinline__ float blockReduceSum1024(float v) {
#pragma unroll
    for (int off = 32; off > 0; off >>= 1)
        v += __shfl_down(v, off, 64);
    __shared__ float smem[16];
    const int lane = threadIdx.x & 63;
    const int wid  = threadIdx.x >> 6;
    __syncthreads();
    if (lane == 0) smem[wid] = v;
    __syncthreads();
    float r = 0.f;
    if (threadIdx.x == 0) {
#pragma unroll
        for (int i = 0; i < 16; ++i) r += smem[i];
    }
    return r;
}

__device__ __forceinline__ double blockReduceSumD256(double v) {
#pragma unroll
    for (int off = 32; off > 0; off >>= 1)
        v += __shfl_down(v, off, 64);
    __shared__ double smem[4];
    const int lane = threadIdx.x & 63;
    const int wid  = threadIdx.x >> 6;
    __syncthreads();
    if (lane == 0) smem[wid] = v;
    __syncthreads();
    double r = 0.0;
    if (threadIdx.x == 0) r = smem[0] + smem[1] + smem[2] + smem[3];
    return r;
}

// ---------------------------------------------------------------------------
// All 512 blocks identical (no specialization tail, no atomics):
//   row phase: block pair (bid>>1 = row r, bid&1 = half h) each stages the
//     FULL fp16 sigmoid row in LDS (60 KB; logits 2nd read is L3-served),
//     BCE over its half of targets, prob_reg over its half of edges from LDS.
//   rec phase: static wave-interleave, one WAVE per edge, lane l holds float4
//     cols {l,l+64,l+128,l+192} of both rows = 8 independent 16B loads.
// Partials -> ws slots (overwrite poison; no init kernel needed).
// ---------------------------------------------------------------------------
__global__ __launch_bounds__(1024, 2)
void fused_kernel(const float4* __restrict__ lg4,
                  const float4* __restrict__ tg4,
                  const float4* __restrict__ p4,
                  const int* __restrict__ pidx,
                  const int* __restrict__ cidx,
                  double* __restrict__ slots) {
    __shared__ __half sprob[NLAB];
    const int tid  = threadIdx.x;
    const int bid  = blockIdx.x;
    const int lane = tid & 63;
    const int r    = bid >> 1;    // batch row
    const int h    = bid & 1;     // which half of targets/edges

    float bces = 0.f, recs = 0.f, ps = 0.f;

    // ---- row phase: sigmoid staging (full row) + BCE (half) ----
    {
        const float4* lrow = lg4 + (size_t)r * NL4;
        const float4* trow = tg4 + (size_t)r * NL4;
        const int tlo = h * HALF4, thi = tlo + HALF4;
        for (int i = tid; i < NL4; i += 1024) {
            const float4 l = lrow[i];
            sprob[4 * i + 0] = __float2half(1.f / (1.f + __expf(-l.x)));
            sprob[4 * i + 1] = __float2half(1.f / (1.f + __expf(-l.y)));
            sprob[4 * i + 2] = __float2half(1.f / (1.f + __expf(-l.z)));
            sprob[4 * i + 3] = __float2half(1.f / (1.f + __expf(-l.w)));
            if (i >= tlo && i < thi) {
                const float4 t = trow[i];
                bces += fmaxf(l.x, 0.f) + log1pf(__expf(-fabsf(l.x))) - l.x * t.x;
                bces += fmaxf(l.y, 0.f) + log1pf(__expf(-fabsf(l.y))) - l.y * t.y;
                bces += fmaxf(l.z, 0.f) + log1pf(__expf(-fabsf(l.z))) - l.z * t.z;
                bces += fmaxf(l.w, 0.f) + log1pf(__expf(-fabsf(l.w))) - l.w * t.w;
            }
        }
        __syncthreads();
        // ---- prob_reg over our half of the edges, from LDS ----
        const int elo = h ? EHALF : 0;
        const int ehi = h ? NE : EHALF;
        for (int e = elo + tid; e < ehi; e += 1024) {
            const float d = __half2float(sprob[cidx[e]]) -
                            __half2float(sprob[pidx[e]]);
            ps += d > 0.f ? d : 0.f;
        }
    }

    // ---- rec phase: static wave-interleave, one wave per edge ----
    {
        const int gw = bid * WAVES_PER_BLK + (tid >> 6);   // global wave id
        for (int e = gw; e < NE; e += TOT_WAVES) {
            const int p = pidx[e];
            const int c = cidx[e];
            const float4* rp = p4 + (size_t)p * (HID / 4) + lane;
            const float4* rc = p4 + (size_t)c * (HID / 4) + lane;
            const float4 a0 = rp[0], a1 = rp[64], a2 = rp[128], a3 = rp[192];
            const float4 b0 = rc[0], b1 = rc[64], b2 = rc[128], b3 = rc[192];
            float dx, dy, dz, dw;
            dx = a0.x - b0.x; dy = a0.y - b0.y; dz = a0.z - b0.z; dw = a0.w - b0.w;
            recs += dx * dx + dy * dy + dz * dz + dw * dw;
            dx = a1.x - b1.x; dy = a1.y - b1.y; dz = a1.z - b1.z; dw = a1.w - b1.w;
            recs += dx * dx + dy * dy + dz * dz + dw * dw;
            dx = a2.x - b2.x; dy = a2.y - b2.y; dz = a2.z - b2.z; dw = a2.w - b2.w;
            recs += dx * dx + dy * dy + dz * dz + dw * dw;
            dx = a3.x - b3.x; dy = a3.y - b3.y; dz = a3.z - b3.z; dw = a3.w - b3.w;
            recs += dx * dx + dy * dy + dz * dz + dw * dw;
        }
    }

    const float rb = blockReduceSum1024(bces);
    const float rr = blockReduceSum1024(recs);
    const float rp = blockReduceSum1024(ps);
    if (tid == 0) {
        slots[bid]              = (double)rb;
        slots[BLOCKS + bid]     = (double)rr;
        slots[2 * BLOCKS + bid] = (double)rp;
    }
}

// finalize: sum the 3 slot arrays, combine, write scalar
__global__ void fin_kernel(const double* __restrict__ slots,
                           float* __restrict__ out) {
    double sb = 0.0, sr = 0.0, sp = 0.0;
    for (int i = threadIdx.x; i < BLOCKS; i += 256) {
        sb += slots[i];
        sr += slots[BLOCKS + i];
        sp += slots[2 * BLOCKS + i];
    }
    sb = blockReduceSumD256(sb);
    sr = blockReduceSumD256(sr);
    sp = blockReduceSumD256(sp);
    if (threadIdx.x == 0) {
        const double bce = sb * (1.0 / ((double)NB * (double)NLAB));
        out[0] = (float)(bce + 5e-5 * sr + 1e-4 * sp);
    }
}

extern "C" void kernel_launch(void* const* d_in, const int* in_sizes, int n_in,
                              void* d_out, int out_size, void* d_ws, size_t ws_size,
                              hipStream_t stream) {
    const float* logits  = (const float*)d_in[0];
    const float* targets = (const float*)d_in[1];
    const float* params  = (const float*)d_in[2];
    const int*   pidx    = (const int*)d_in[3];
    const int*   cidx    = (const int*)d_in[4];
    double* slots = (double*)d_ws;
    float*  out   = (float*)d_out;

    fused_kernel<<<BLOCKS, 1024, 0, stream>>>(
        (const float4*)logits, (const float4*)targets, (const float4*)params,
        pidx, cidx, slots);
    fin_kernel<<<1, 256, 0, stream>>>(slots, out);
}

// Round 6
// 238.251 us; speedup vs baseline: 2.0251x; 1.0179x over previous
//
#include <hip/hip_runtime.h>
#include <hip/hip_fp16.h>

#define NLAB 30000
#define HID  1024
#define NB   256
#define NE   (NLAB - 1)

#define BLOCKS 512               // 2 per CU, one scheduling round, all identical
#define WAVES_PER_BLK 16
#define TOT_WAVES (BLOCKS * WAVES_PER_BLK)   // 8192
#define NL4 (NLAB / 4)           // 7500 float4 per row
#define HALF4 (NL4 / 2)          // 3750
#define EHALF 15000              // edge split point between the 2 row-sharers

// float block reduce, 1024 threads (16 waves)
__device__ __forceinline__ float blockReduceSum1024(float v) {
#pragma unroll
    for (int off = 32; off > 0; off >>= 1)
        v += __shfl_down(v, off, 64);
    __shared__ float smem[16];
    const int lane = threadIdx.x & 63;
    const int wid  = threadIdx.x >> 6;
    __syncthreads();
    if (lane == 0) smem[wid] = v;
    __syncthreads();
    float r = 0.f;
    if (threadIdx.x == 0) {
#pragma unroll
        for (int i = 0; i < 16; ++i) r += smem[i];
    }
    return r;
}

__device__ __forceinline__ double blockReduceSumD256(double v) {
#pragma unroll
    for (int off = 32; off > 0; off >>= 1)
        v += __shfl_down(v, off, 64);
    __shared__ double smem[4];
    const int lane = threadIdx.x & 63;
    const int wid  = threadIdx.x >> 6;
    __syncthreads();
    if (lane == 0) smem[wid] = v;
    __syncthreads();
    double r = 0.0;
    if (threadIdx.x == 0) r = smem[0] + smem[1] + smem[2] + smem[3];
    return r;
}

// ---------------------------------------------------------------------------
// All 512 blocks identical:
//   row phase: block pair (r=bid>>1, h=bid&1) stages the FULL fp16 sigmoid
//     row in LDS (60 KB), BCE over its half of targets, prob_reg over its
//     half of edges from LDS. BCE/sigmoid share one exp+rcp+log.
//   rec phase: static wave-interleave, one WAVE per edge; next edge's indices
//     prefetched BEFORE the 8 row loads issue, so each wave keeps ~8-10
//     independent 16B loads in flight (launch_bounds caps VGPR at 64 to hold
//     2 blocks/CU = 32 waves).
// ---------------------------------------------------------------------------
__global__ __launch_bounds__(1024, 8)
void fused_kernel(const float4* __restrict__ lg4,
                  const float4* __restrict__ tg4,
                  const float4* __restrict__ p4,
                  const int* __restrict__ pidx,
                  const int* __restrict__ cidx,
                  double* __restrict__ slots) {
    __shared__ __half sprob[NLAB];
    const int tid  = threadIdx.x;
    const int bid  = blockIdx.x;
    const int lane = tid & 63;
    const int r    = bid >> 1;    // batch row
    const int h    = bid & 1;     // which half of targets/edges

    float bces = 0.f, recs = 0.f, ps = 0.f;

    // ---- row phase: sigmoid staging (full row) + BCE (half) ----
    {
        const float4* lrow = lg4 + (size_t)r * NL4;
        const float4* trow = tg4 + (size_t)r * NL4;
        const int tlo = h * HALF4, thi = tlo + HALF4;
        for (int i = tid; i < NL4; i += 1024) {
            const float4 l = lrow[i];
            // e = exp(-|l|); inv = 1/(1+e) = sigmoid(|l|)
            const float e0 = __expf(-fabsf(l.x)), i0 = __frcp_rn(1.f + e0);
            const float e1 = __expf(-fabsf(l.y)), i1 = __frcp_rn(1.f + e1);
            const float e2 = __expf(-fabsf(l.z)), i2 = __frcp_rn(1.f + e2);
            const float e3 = __expf(-fabsf(l.w)), i3 = __frcp_rn(1.f + e3);
            const float s0 = l.x > 0.f ? i0 : 1.f - i0;
            const float s1 = l.y > 0.f ? i1 : 1.f - i1;
            const float s2 = l.z > 0.f ? i2 : 1.f - i2;
            const float s3 = l.w > 0.f ? i3 : 1.f - i3;
            sprob[4 * i + 0] = __float2half(s0);
            sprob[4 * i + 1] = __float2half(s1);
            sprob[4 * i + 2] = __float2half(s2);
            sprob[4 * i + 3] = __float2half(s3);
            if (i >= tlo && i < thi) {
                const float4 t = trow[i];
                // softplus(l) = max(l,0) - log(sigmoid(|l|))
                bces += fmaxf(l.x, 0.f) - __logf(i0) - l.x * t.x;
                bces += fmaxf(l.y, 0.f) - __logf(i1) - l.y * t.y;
                bces += fmaxf(l.z, 0.f) - __logf(i2) - l.z * t.z;
                bces += fmaxf(l.w, 0.f) - __logf(i3) - l.w * t.w;
            }
        }
        __syncthreads();
        // ---- prob_reg over our half of the edges, from LDS ----
        const int elo = h ? EHALF : 0;
        const int ehi = h ? NE : EHALF;
        for (int e = elo + tid; e < ehi; e += 1024) {
            const float d = __half2float(sprob[cidx[e]]) -
                            __half2float(sprob[pidx[e]]);
            ps += d > 0.f ? d : 0.f;
        }
    }

    // ---- rec phase: wave-per-edge, index prefetch breaks the dep chain ----
    {
        const int gw = bid * WAVES_PER_BLK + (tid >> 6);   // global wave id
        int e = gw;
        int p = 0, c = 0;
        if (e < NE) { p = pidx[e]; c = cidx[e]; }
        while (e < NE) {
            const int en = e + TOT_WAVES;
            int pn = 0, cn = 0;
            if (en < NE) { pn = pidx[en]; cn = cidx[en]; }   // prefetch
            const float4* rp = p4 + (size_t)p * (HID / 4) + lane;
            const float4* rc = p4 + (size_t)c * (HID / 4) + lane;
            const float4 a0 = rp[0], a1 = rp[64], a2 = rp[128], a3 = rp[192];
            const float4 b0 = rc[0], b1 = rc[64], b2 = rc[128], b3 = rc[192];
            float dx, dy, dz, dw;
            dx = a0.x - b0.x; dy = a0.y - b0.y; dz = a0.z - b0.z; dw = a0.w - b0.w;
            recs += dx * dx + dy * dy + dz * dz + dw * dw;
            dx = a1.x - b1.x; dy = a1.y - b1.y; dz = a1.z - b1.z; dw = a1.w - b1.w;
            recs += dx * dx + dy * dy + dz * dz + dw * dw;
            dx = a2.x - b2.x; dy = a2.y - b2.y; dz = a2.z - b2.z; dw = a2.w - b2.w;
            recs += dx * dx + dy * dy + dz * dz + dw * dw;
            dx = a3.x - b3.x; dy = a3.y - b3.y; dz = a3.z - b3.z; dw = a3.w - b3.w;
            recs += dx * dx + dy * dy + dz * dz + dw * dw;
            e = en; p = pn; c = cn;
        }
    }

    const float rb = blockReduceSum1024(bces);
    const float rr = blockReduceSum1024(recs);
    const float rp = blockReduceSum1024(ps);
    if (tid == 0) {
        slots[bid]              = (double)rb;
        slots[BLOCKS + bid]     = (double)rr;
        slots[2 * BLOCKS + bid] = (double)rp;
    }
}

// finalize: sum the 3 slot arrays, combine, write scalar
__global__ void fin_kernel(const double* __restrict__ slots,
                           float* __restrict__ out) {
    double sb = 0.0, sr = 0.0, sp = 0.0;
    for (int i = threadIdx.x; i < BLOCKS; i += 256) {
        sb += slots[i];
        sr += slots[BLOCKS + i];
        sp += slots[2 * BLOCKS + i];
    }
    sb = blockReduceSumD256(sb);
    sr = blockReduceSumD256(sr);
    sp = blockReduceSumD256(sp);
    if (threadIdx.x == 0) {
        const double bce = sb * (1.0 / ((double)NB * (double)NLAB));
        out[0] = (float)(bce + 5e-5 * sr + 1e-4 * sp);
    }
}

extern "C" void kernel_launch(void* const* d_in, const int* in_sizes, int n_in,
                              void* d_out, int out_size, void* d_ws, size_t ws_size,
                              hipStream_t stream) {
    const float* logits  = (const float*)d_in[0];
    const float* targets = (const float*)d_in[1];
    const float* params  = (const float*)d_in[2];
    const int*   pidx    = (const int*)d_in[3];
    const int*   cidx    = (const int*)d_in[4];
    double* slots = (double*)d_ws;
    float*  out   = (float*)d_out;

    fused_kernel<<<BLOCKS, 1024, 0, stream>>>(
        (const float4*)logits, (const float4*)targets, (const float4*)params,
        pidx, cidx, slots);
    fin_kernel<<<1, 256, 0, stream>>>(slots, out);
}